// Round 2
// baseline (468.593 us; speedup 1.0000x reference)
//
#include <hip/hip_runtime.h>

#define PTOT   1048576
#define NRAYS  8192
#define THRESH 1e-4f

__device__ __forceinline__ float raw2alpha_f(float d){
    // 1 - exp(-softplus(d + ACT_SHIFT) * INTERVAL), ACT_SHIFT=-4, INTERVAL=0.5
    // == 1 - (1 + e^(d-4))^(-1/2)
    return 1.0f - rsqrtf(1.0f + __expf(d - 4.0f));
}

// ---------------- kernel 1: per-point density alpha + gate ----------------
__global__ __launch_bounds__(256) void k_point(
    const float* __restrict__ pts, const float* __restrict__ vdirs,
    const int* __restrict__ ray_id,
    const float* __restrict__ Wd1, const float* __restrict__ bd1,
    const float* __restrict__ Wd2, const float* __restrict__ Wg,
    float* __restrict__ alpha0, float* __restrict__ g0a, int* __restrict__ eea)
{
    __shared__ float4 WD4[128];   // {Wd1[0][i], Wd1[1][i], Wd1[2][i], bd1[i]}
    __shared__ float  WD2s[128];
    __shared__ float  WGs[8][6];  // WGs[e][k]
    int t = threadIdx.x;
    if (t < 128){
        WD4[t] = make_float4(Wd1[t], Wd1[128+t], Wd1[256+t], bd1[t]);
        WD2s[t] = Wd2[t];
    }
    if (t < 48) WGs[t & 7][t >> 3] = Wg[t];   // Wg[k][e] flat = k*8+e
    __syncthreads();

    int base = blockIdx.x * 2048 + t;         // PT=8 points, lane-interleaved
    float px[8], py[8], pz[8], dens[8];
    #pragma unroll
    for (int j=0;j<8;j++){
        int p = base + j*256;
        px[j]=pts[3*p]; py[j]=pts[3*p+1]; pz[j]=pts[3*p+2];
        dens[j]=0.f;
    }
    for (int i=0;i<128;i++){
        float4 w = WD4[i]; float w2 = WD2s[i];
        #pragma unroll
        for (int j=0;j<8;j++){
            float h = fmaf(px[j],w.x, fmaf(py[j],w.y, fmaf(pz[j],w.z, w.w)));
            h = fmaxf(h, 0.f);
            dens[j] = fmaf(h, w2, dens[j]);
        }
    }
    #pragma unroll
    for (int j=0;j<8;j++){
        float a = raw2alpha_f(dens[j]);
        alpha0[base + j*256] = (a > THRESH) ? a : 0.f;
    }
    // gate: logits over 8 experts on x=[pts, viewdirs[ray_id]], top-2, renorm
    float vx[8],vy[8],vz[8];
    #pragma unroll
    for (int j=0;j<8;j++){
        int rid = ray_id[base + j*256];
        vx[j]=vdirs[3*rid]; vy[j]=vdirs[3*rid+1]; vz[j]=vdirs[3*rid+2];
    }
    float m0[8], m1[8]; int i0[8], i1[8];
    #pragma unroll
    for (int j=0;j<8;j++){ m0[j]=-3.0e38f; m1[j]=-3.0e38f; i0[j]=0; i1[j]=0; }
    for (int e=0;e<8;e++){
        float w0=WGs[e][0],w1=WGs[e][1],w2=WGs[e][2],w3=WGs[e][3],w4=WGs[e][4],w5=WGs[e][5];
        #pragma unroll
        for (int j=0;j<8;j++){
            float l = px[j]*w0 + py[j]*w1 + pz[j]*w2 + vx[j]*w3 + vy[j]*w4 + vz[j]*w5;
            if (l > m0[j]){ m1[j]=m0[j]; i1[j]=i0[j]; m0[j]=l; i0[j]=e; }
            else if (l > m1[j]){ m1[j]=l; i1[j]=e; }
        }
    }
    #pragma unroll
    for (int j=0;j<8;j++){
        // renormalized top-2 of softmax == softmax over the two top logits
        float g0 = __fdividef(1.0f, 1.0f + __expf(m1[j]-m0[j]));
        g0a[base + j*256] = g0;
        eea[base + j*256] = i0[j] | (i1[j] << 8);
    }
}

// ---------------- kernel 2: ray start offsets (binary search) ----------------
__global__ __launch_bounds__(256) void k_rayoff(const int* __restrict__ ray_id,
                                                int* __restrict__ ray_off)
{
    int r = blockIdx.x*256 + threadIdx.x;
    if (r > NRAYS) return;
    int lo = 0, hi = PTOT;
    while (lo < hi){ int mid = (lo+hi) >> 1; if (ray_id[mid] < r) lo = mid+1; else hi = mid; }
    ray_off[r] = lo;
}

// ---------------- kernel 3: per-ray transmittance scan -> keep mask ----------------
__global__ __launch_bounds__(256) void k_scan0(const float* __restrict__ alpha0,
                                               const int* __restrict__ ray_off,
                                               unsigned char* __restrict__ keep)
{
    int wid  = (blockIdx.x*blockDim.x + threadIdx.x) >> 6;   // wave = ray
    int lane = threadIdx.x & 63;
    if (wid >= NRAYS) return;
    int s = ray_off[wid], e = ray_off[wid+1];
    float carry = 1.f;
    for (int c = s; c < e; c += 64){
        int p = c + lane;
        float a = (p < e) ? alpha0[p] : 0.f;
        float f = 1.f - a;
        float incl = f;
        #pragma unroll
        for (int d=1; d<64; d<<=1){ float tt = __shfl_up(incl, d); if (lane >= d) incl *= tt; }
        float excl = __shfl_up(incl, 1); if (lane == 0) excl = 1.f;
        float T  = carry * excl;      // transmittance before this point
        float w0 = a * T;
        if (p < e) keep[p] = (w0 > THRESH) ? (unsigned char)1 : (unsigned char)0;
        carry *= __shfl(incl, 63);
    }
}

// ---------------- kernel 4a: exact per-expert counts ----------------
__global__ __launch_bounds__(256) void k_count(const unsigned char* __restrict__ keep,
                                               const int* __restrict__ eea,
                                               int* __restrict__ cntA)
{
    __shared__ int lcnt[8];
    int t = threadIdx.x;
    if (t < 8) lcnt[t] = 0;
    __syncthreads();
    int p = blockIdx.x*256 + t;
    if (keep[p]){
        int ee = eea[p];
        atomicAdd(&lcnt[ee & 255], 1);
        atomicAdd(&lcnt[(ee >> 8) & 255], 1);
    }
    __syncthreads();
    if (t < 8 && lcnt[t]) atomicAdd(&cntA[t], lcnt[t]);
}

// ---------------- kernel 4b: exclusive prefix offsets ----------------
__global__ void k_offsets(const int* __restrict__ cntA,
                          int* __restrict__ offA, int* __restrict__ curA)
{
    if (threadIdx.x == 0 && blockIdx.x == 0){
        int acc = 0;
        for (int e = 0; e < 8; e++){ offA[e] = acc; acc += cntA[e]; curA[e] = 0; }
    }
}

// ---------------- kernel 4c: fill entries (exact, no capacity drops) ----------------
__global__ __launch_bounds__(256) void k_fill(const unsigned char* __restrict__ keep,
                                              const float* __restrict__ g0a,
                                              const int* __restrict__ eea,
                                              const int* __restrict__ offA,
                                              int* __restrict__ curA,
                                              int2* __restrict__ ent)
{
    __shared__ int lcnt[8], lbase[8];
    int t = threadIdx.x;
    if (t < 8) lcnt[t] = 0;
    __syncthreads();
    int p = blockIdx.x*256 + t;
    int k = keep[p];
    float g0 = g0a[p];
    int ee = eea[p];
    int e0 = ee & 255, e1 = (ee >> 8) & 255;
    int r0 = 0, r1 = 0;
    if (k){
        r0 = atomicAdd(&lcnt[e0], 1);
        r1 = atomicAdd(&lcnt[e1], 1);
    }
    __syncthreads();
    if (t < 8) lbase[t] = offA[t] + atomicAdd(&curA[t], lcnt[t]);
    __syncthreads();
    if (k){
        ent[lbase[e0] + r0] = make_int2(p, __float_as_int(g0));
        ent[lbase[e1] + r1] = make_int2(p, __float_as_int(1.0f - g0));
    }
}

// ---------------- kernel 5: expert MLPs (the heavy one) ----------------
// 512 blocks per expert (covers worst case 1M entries/expert), 256 threads,
// 8 entries/thread (lane-interleaved, all same expert -> wave-uniform weights)
__global__ __launch_bounds__(256) void k_expert(
    const int2* __restrict__ ent, const int* __restrict__ cntA,
    const int* __restrict__ offA,
    const float* __restrict__ pts, const float* __restrict__ vdirs,
    const int* __restrict__ ray_id,
    const float* __restrict__ We1, const float* __restrict__ be1,
    const float* __restrict__ Wrgb, const float* __restrict__ Walpha,
    float* __restrict__ rgbacc)
{
    int e    = blockIdx.x >> 9;
    int bi   = blockIdx.x & 511;
    int n    = cntA[e];
    int base = bi * 2048;
    if (base >= n) return;

    __shared__ float4 WA[128];   // We1[e][0..3][i]
    __shared__ float4 WB[128];   // We1[e][4][i], We1[e][5][i], be1[e][i], Walpha[e][i]
    __shared__ float4 WC[128];   // Wrgb[e][i][0..2], 0
    int t = threadIdx.x;
    if (t < 128){
        const float* w = We1 + e*768;
        WA[t] = make_float4(w[t], w[128+t], w[256+t], w[384+t]);
        WB[t] = make_float4(w[512+t], w[640+t], be1[e*128+t], Walpha[e*128+t]);
        const float* wr = Wrgb + e*384 + 3*t;
        WC[t] = make_float4(wr[0], wr[1], wr[2], 0.f);
    }
    __syncthreads();

    const int2* eb = ent + offA[e];
    float x0[8],x1[8],x2[8],x3[8],x4[8],x5[8],gg[8];
    float ar[8],ag[8],ab[8],aa[8];
    int   pid[8];
    #pragma unroll
    for (int j=0;j<8;j++){
        int idx = base + t + j*256;
        bool v = idx < n;
        int2 rec = v ? eb[idx] : make_int2(0, 0);
        pid[j] = rec.x;
        gg[j]  = v ? __int_as_float(rec.y) : 0.f;
        int pp = rec.x;
        x0[j]=pts[3*pp]; x1[j]=pts[3*pp+1]; x2[j]=pts[3*pp+2];
        int rid = ray_id[pp];
        x3[j]=vdirs[3*rid]; x4[j]=vdirs[3*rid+1]; x5[j]=vdirs[3*rid+2];
        ar[j]=0.f; ag[j]=0.f; ab[j]=0.f; aa[j]=0.f;
    }
    #pragma unroll 2
    for (int i=0;i<128;i++){
        float4 wa = WA[i], wb = WB[i], wc = WC[i];
        #pragma unroll
        for (int j=0;j<8;j++){
            float h = fmaf(x0[j],wa.x, fmaf(x1[j],wa.y, fmaf(x2[j],wa.z,
                      fmaf(x3[j],wa.w, fmaf(x4[j],wb.x, fmaf(x5[j],wb.y, wb.z))))));
            h = fmaxf(h, 0.f);
            ar[j] = fmaf(h, wc.x, ar[j]);
            ag[j] = fmaf(h, wc.y, ag[j]);
            ab[j] = fmaf(h, wc.z, ab[j]);
            aa[j] = fmaf(h, wb.w, aa[j]);
        }
    }
    #pragma unroll
    for (int j=0;j<8;j++){
        int idx = base + t + j*256;
        if (idx < n){
            float sr = __fdividef(1.0f, 1.0f + __expf(-ar[j]));
            float sg = __fdividef(1.0f, 1.0f + __expf(-ag[j]));
            float sb = __fdividef(1.0f, 1.0f + __expf(-ab[j]));
            float a  = raw2alpha_f(aa[j]);
            float g  = gg[j];
            float* dst = rgbacc + 4*(size_t)pid[j];
            atomicAdd(dst+0, g*sr);
            atomicAdd(dst+1, g*sg);
            atomicAdd(dst+2, g*sb);
            atomicAdd(dst+3, g*a);
        }
    }
}

// ---------------- kernel 6: final per-ray composite ----------------
__global__ __launch_bounds__(256) void k_scan1(const float4* __restrict__ rgbacc,
                                               const int* __restrict__ ray_off,
                                               const float* __restrict__ bg,
                                               float* __restrict__ out)
{
    int wid  = (blockIdx.x*blockDim.x + threadIdx.x) >> 6;   // wave = ray
    int lane = threadIdx.x & 63;
    if (wid >= NRAYS) return;
    int s = ray_off[wid], e = ray_off[wid+1];
    float carry = 1.f;
    float accx = 0.f, accy = 0.f, accz = 0.f;
    for (int c = s; c < e; c += 64){
        int p = c + lane;
        float4 v = (p < e) ? rgbacc[p] : make_float4(0.f,0.f,0.f,0.f);
        float a = v.w;
        float f = 1.f - a;
        float incl = f;
        #pragma unroll
        for (int d=1; d<64; d<<=1){ float tt = __shfl_up(incl, d); if (lane >= d) incl *= tt; }
        float excl = __shfl_up(incl, 1); if (lane == 0) excl = 1.f;
        float w = a * carry * excl;
        accx = fmaf(w, v.x, accx);
        accy = fmaf(w, v.y, accy);
        accz = fmaf(w, v.z, accz);
        carry *= __shfl(incl, 63);
    }
    #pragma unroll
    for (int d=32; d; d>>=1){
        accx += __shfl_xor(accx, d);
        accy += __shfl_xor(accy, d);
        accz += __shfl_xor(accz, d);
    }
    if (lane == 0){
        out[3*wid+0] = accx + carry*bg[0];
        out[3*wid+1] = accy + carry*bg[1];
        out[3*wid+2] = accz + carry*bg[2];
    }
}

extern "C" void kernel_launch(void* const* d_in, const int* in_sizes, int n_in,
                              void* d_out, int out_size, void* d_ws, size_t ws_size,
                              hipStream_t stream)
{
    const float* pts    = (const float*)d_in[0];
    const float* vdirs  = (const float*)d_in[1];
    const float* bg     = (const float*)d_in[2];
    const float* Wd1    = (const float*)d_in[3];
    const float* bd1    = (const float*)d_in[4];
    const float* Wd2    = (const float*)d_in[5];
    const float* Wg     = (const float*)d_in[6];
    const float* We1    = (const float*)d_in[7];
    const float* be1    = (const float*)d_in[8];
    const float* Wrgb   = (const float*)d_in[9];
    const float* Walpha = (const float*)d_in[10];
    const int*   ray_id = (const int*)d_in[11];
    float* out = (float*)d_out;

    char* ws = (char*)d_ws;
    size_t off = 0;
    float* alpha0        = (float*)(ws + off); off += (size_t)PTOT*4;     // 4MB
    float* g0a           = (float*)(ws + off); off += (size_t)PTOT*4;     // 4MB
    int*   eea           = (int*)  (ws + off); off += (size_t)PTOT*4;     // 4MB
    unsigned char* keep  = (unsigned char*)(ws + off); off += (size_t)PTOT; // 1MB
    int*   ray_off       = (int*)  (ws + off); off += 65536;
    int*   cntA          = (int*)  (ws + off); off += 256;
    int*   offA          = (int*)  (ws + off); off += 256;
    int*   curA          = (int*)  (ws + off); off += 256;
    off = (off + 255) & ~(size_t)255;
    int2*  ent           = (int2*) (ws + off); off += (size_t)2*PTOT*8;   // 16MB (exact worst case)
    float* rgbacc        = (float*)(ws + off); off += (size_t)PTOT*16;    // 16MB

    hipMemsetAsync(cntA, 0, 8*sizeof(int), stream);
    hipMemsetAsync(rgbacc, 0, (size_t)PTOT*16, stream);

    k_point  <<<PTOT/2048, 256, 0, stream>>>(pts, vdirs, ray_id, Wd1, bd1, Wd2, Wg,
                                             alpha0, g0a, eea);
    k_rayoff <<<(NRAYS+256)/256, 256, 0, stream>>>(ray_id, ray_off);
    k_scan0  <<<NRAYS*64/256, 256, 0, stream>>>(alpha0, ray_off, keep);
    k_count  <<<PTOT/256, 256, 0, stream>>>(keep, eea, cntA);
    k_offsets<<<1, 64, 0, stream>>>(cntA, offA, curA);
    k_fill   <<<PTOT/256, 256, 0, stream>>>(keep, g0a, eea, offA, curA, ent);
    k_expert <<<8*512, 256, 0, stream>>>(ent, cntA, offA, pts, vdirs, ray_id,
                                         We1, be1, Wrgb, Walpha, rgbacc);
    k_scan1  <<<NRAYS*64/256, 256, 0, stream>>>((const float4*)rgbacc, ray_off, bg, out);
}

// Round 3
// 251.854 us; speedup vs baseline: 1.8606x; 1.8606x over previous
//
#include <hip/hip_runtime.h>

#define PTOT   1048576
#define NRAYS  8192
#define THRESH 1e-4f

__device__ __forceinline__ float raw2alpha_f(float d){
    // 1 - exp(-softplus(d + ACT_SHIFT) * INTERVAL), ACT_SHIFT=-4, INTERVAL=0.5
    // == 1 - (1 + e^(d-4))^(-1/2)
    return 1.0f - rsqrtf(1.0f + __expf(d - 4.0f));
}

// ---------------- kernel 1: per-point density alpha + gate ----------------
__global__ __launch_bounds__(256) void k_point(
    const float* __restrict__ pts, const float* __restrict__ vdirs,
    const int* __restrict__ ray_id,
    const float* __restrict__ Wd1, const float* __restrict__ bd1,
    const float* __restrict__ Wd2, const float* __restrict__ Wg,
    float* __restrict__ alpha0, float* __restrict__ g0a, int* __restrict__ eea)
{
    __shared__ float4 WD4[128];   // {Wd1[0][i], Wd1[1][i], Wd1[2][i], bd1[i]}
    __shared__ float  WD2s[128];
    __shared__ float  WGs[8][6];  // WGs[e][k]
    int t = threadIdx.x;
    if (t < 128){
        WD4[t] = make_float4(Wd1[t], Wd1[128+t], Wd1[256+t], bd1[t]);
        WD2s[t] = Wd2[t];
    }
    if (t < 48) WGs[t & 7][t >> 3] = Wg[t];   // Wg[k][e] flat = k*8+e
    __syncthreads();

    int base = blockIdx.x * 2048 + t;         // PT=8 points, lane-interleaved
    float px[8], py[8], pz[8], dens[8];
    #pragma unroll
    for (int j=0;j<8;j++){
        int p = base + j*256;
        px[j]=pts[3*p]; py[j]=pts[3*p+1]; pz[j]=pts[3*p+2];
        dens[j]=0.f;
    }
    for (int i=0;i<128;i++){
        float4 w = WD4[i]; float w2 = WD2s[i];
        #pragma unroll
        for (int j=0;j<8;j++){
            float h = fmaf(px[j],w.x, fmaf(py[j],w.y, fmaf(pz[j],w.z, w.w)));
            h = fmaxf(h, 0.f);
            dens[j] = fmaf(h, w2, dens[j]);
        }
    }
    #pragma unroll
    for (int j=0;j<8;j++){
        float a = raw2alpha_f(dens[j]);
        alpha0[base + j*256] = (a > THRESH) ? a : 0.f;
    }
    float vx[8],vy[8],vz[8];
    #pragma unroll
    for (int j=0;j<8;j++){
        int rid = ray_id[base + j*256];
        vx[j]=vdirs[3*rid]; vy[j]=vdirs[3*rid+1]; vz[j]=vdirs[3*rid+2];
    }
    float m0[8], m1[8]; int i0[8], i1[8];
    #pragma unroll
    for (int j=0;j<8;j++){ m0[j]=-3.0e38f; m1[j]=-3.0e38f; i0[j]=0; i1[j]=0; }
    for (int e=0;e<8;e++){
        float w0=WGs[e][0],w1=WGs[e][1],w2=WGs[e][2],w3=WGs[e][3],w4=WGs[e][4],w5=WGs[e][5];
        #pragma unroll
        for (int j=0;j<8;j++){
            float l = px[j]*w0 + py[j]*w1 + pz[j]*w2 + vx[j]*w3 + vy[j]*w4 + vz[j]*w5;
            if (l > m0[j]){ m1[j]=m0[j]; i1[j]=i0[j]; m0[j]=l; i0[j]=e; }
            else if (l > m1[j]){ m1[j]=l; i1[j]=e; }
        }
    }
    #pragma unroll
    for (int j=0;j<8;j++){
        // renormalized top-2 of softmax == softmax over the two top logits
        float g0 = __fdividef(1.0f, 1.0f + __expf(m1[j]-m0[j]));
        g0a[base + j*256] = g0;
        eea[base + j*256] = i0[j] | (i1[j] << 8);
    }
}

// ---------------- kernel 2: ray start offsets (binary search) ----------------
__global__ __launch_bounds__(256) void k_rayoff(const int* __restrict__ ray_id,
                                                int* __restrict__ ray_off)
{
    int r = blockIdx.x*256 + threadIdx.x;
    if (r > NRAYS) return;
    int lo = 0, hi = PTOT;
    while (lo < hi){ int mid = (lo+hi) >> 1; if (ray_id[mid] < r) lo = mid+1; else hi = mid; }
    ray_off[r] = lo;
}

// ---------------- kernel 3: per-ray transmittance scan -> keep mask ----------------
__global__ __launch_bounds__(256) void k_scan0(const float* __restrict__ alpha0,
                                               const int* __restrict__ ray_off,
                                               unsigned char* __restrict__ keep)
{
    int wid  = (blockIdx.x*blockDim.x + threadIdx.x) >> 6;   // wave = ray
    int lane = threadIdx.x & 63;
    if (wid >= NRAYS) return;
    int s = ray_off[wid], e = ray_off[wid+1];
    float carry = 1.f;
    for (int c = s; c < e; c += 64){
        int p = c + lane;
        float a = (p < e) ? alpha0[p] : 0.f;
        float f = 1.f - a;
        float incl = f;
        #pragma unroll
        for (int d=1; d<64; d<<=1){ float tt = __shfl_up(incl, d); if (lane >= d) incl *= tt; }
        float excl = __shfl_up(incl, 1); if (lane == 0) excl = 1.f;
        float T  = carry * excl;      // transmittance before this point
        float w0 = a * T;
        if (p < e) keep[p] = (w0 > THRESH) ? (unsigned char)1 : (unsigned char)0;
        carry *= __shfl(incl, 63);
    }
}

// ---------------- kernel 4a: exact per-expert counts (ballot-based) ----------------
__global__ __launch_bounds__(256) void k_count(const unsigned char* __restrict__ keep,
                                               const int* __restrict__ eea,
                                               int* __restrict__ cntA)
{
    __shared__ int wc[4][8];
    int t = threadIdx.x, lane = t & 63, w = t >> 6;
    int c[8];
    #pragma unroll
    for (int e=0;e<8;e++) c[e]=0;
    int base = blockIdx.x * 2048;
    for (int j=0;j<8;j++){
        int p = base + (j*4 + w)*64 + lane;
        int k = keep[p];
        int ee = eea[p];
        int e0 = ee & 255, e1 = (ee >> 8) & 255;
        #pragma unroll
        for (int e=0;e<8;e++){
            unsigned long long m0 = __ballot(k && e0==e);
            unsigned long long m1 = __ballot(k && e1==e);
            c[e] += __popcll(m0) + __popcll(m1);
        }
    }
    if (lane == 0){
        #pragma unroll
        for (int e=0;e<8;e++) wc[w][e] = c[e];
    }
    __syncthreads();
    if (t < 8){
        int s = wc[0][t]+wc[1][t]+wc[2][t]+wc[3][t];
        if (s) atomicAdd(&cntA[t], s);
    }
}

// ---------------- kernel 4b: exclusive prefix offsets ----------------
__global__ void k_offsets(const int* __restrict__ cntA,
                          int* __restrict__ offA, int* __restrict__ curA)
{
    if (threadIdx.x == 0 && blockIdx.x == 0){
        int acc = 0;
        for (int e = 0; e < 8; e++){ offA[e] = acc; acc += cntA[e]; curA[e] = 0; }
    }
}

// ---------------- kernel 4c: fill entries (ballot-ranked, exact) ----------------
// entry.x = pid | (slot << 30), entry.y = gate weight bits
__global__ __launch_bounds__(256) void k_fill(const unsigned char* __restrict__ keep,
                                              const float* __restrict__ g0a,
                                              const int* __restrict__ eea,
                                              const int* __restrict__ offA,
                                              int* __restrict__ curA,
                                              int2* __restrict__ ent)
{
    __shared__ int wc[4][8];
    __shared__ int wb[4][8];
    int t = threadIdx.x, lane = t & 63, w = t >> 6;
    unsigned long long lt = (1ull << lane) - 1ull;
    int base = blockIdx.x * 2048;

    // phase A: per-wave per-expert counts
    int c[8];
    #pragma unroll
    for (int e=0;e<8;e++) c[e]=0;
    for (int j=0;j<8;j++){
        int p = base + (j*4 + w)*64 + lane;
        int k = keep[p];
        int ee = eea[p];
        int e0 = ee & 255, e1 = (ee >> 8) & 255;
        #pragma unroll
        for (int e=0;e<8;e++){
            unsigned long long m0 = __ballot(k && e0==e);
            unsigned long long m1 = __ballot(k && e1==e);
            c[e] += __popcll(m0) + __popcll(m1);
        }
    }
    if (lane == 0){
        #pragma unroll
        for (int e=0;e<8;e++) wc[w][e] = c[e];
    }
    __syncthreads();
    if (t < 8){
        int tot = wc[0][t]+wc[1][t]+wc[2][t]+wc[3][t];
        int b = offA[t] + (tot ? atomicAdd(&curA[t], tot) : 0);
        wb[0][t] = b; b += wc[0][t];
        wb[1][t] = b; b += wc[1][t];
        wb[2][t] = b; b += wc[2][t];
        wb[3][t] = b;
    }
    __syncthreads();

    // phase B: write entries at ballot ranks
    int cur[8];
    #pragma unroll
    for (int e=0;e<8;e++) cur[e] = wb[w][e];
    for (int j=0;j<8;j++){
        int p = base + (j*4 + w)*64 + lane;
        int k = keep[p];
        float g0 = g0a[p];
        int ee = eea[p];
        int e0 = ee & 255, e1 = (ee >> 8) & 255;
        #pragma unroll
        for (int e=0;e<8;e++){
            unsigned long long m0 = __ballot(k && e0==e);
            unsigned long long m1 = __ballot(k && e1==e);
            if (k && e0==e)
                ent[cur[e] + __popcll(m0 & lt)] = make_int2(p, __float_as_int(g0));
            if (k && e1==e)
                ent[cur[e] + __popcll(m0) + __popcll(m1 & lt)] =
                    make_int2(p | (1 << 30), __float_as_int(1.0f - g0));
            cur[e] += __popcll(m0) + __popcll(m1);
        }
    }
}

// ---------------- kernel 5: expert MLPs (the heavy one) ----------------
// 512 blocks/expert, 256 threads, 8 entries/thread. NO atomics: each entry
// owns res[2*pid + slot] exclusively -> plain float4 store.
__global__ __launch_bounds__(256) void k_expert(
    const int2* __restrict__ ent, const int* __restrict__ cntA,
    const int* __restrict__ offA,
    const float* __restrict__ pts, const float* __restrict__ vdirs,
    const int* __restrict__ ray_id,
    const float* __restrict__ We1, const float* __restrict__ be1,
    const float* __restrict__ Wrgb, const float* __restrict__ Walpha,
    float4* __restrict__ res)
{
    int e    = blockIdx.x >> 9;
    int bi   = blockIdx.x & 511;
    int n    = cntA[e];
    int base = bi * 2048;
    if (base >= n) return;

    __shared__ float4 WA[128];   // We1[e][0..3][i]
    __shared__ float4 WB[128];   // We1[e][4][i], We1[e][5][i], be1[e][i], Walpha[e][i]
    __shared__ float4 WC[128];   // Wrgb[e][i][0..2], 0
    int t = threadIdx.x;
    if (t < 128){
        const float* w = We1 + e*768;
        WA[t] = make_float4(w[t], w[128+t], w[256+t], w[384+t]);
        WB[t] = make_float4(w[512+t], w[640+t], be1[e*128+t], Walpha[e*128+t]);
        const float* wr = Wrgb + e*384 + 3*t;
        WC[t] = make_float4(wr[0], wr[1], wr[2], 0.f);
    }
    __syncthreads();

    const int2* eb = ent + offA[e];
    float x0[8],x1[8],x2[8],x3[8],x4[8],x5[8],gg[8];
    float ar[8],ag[8],ab[8],aa[8];
    int   rid8[8];
    #pragma unroll
    for (int j=0;j<8;j++){
        int idx = base + t + j*256;
        bool v = idx < n;
        int2 rec = v ? eb[idx] : make_int2(0, 0);
        rid8[j] = rec.x;
        gg[j]  = v ? __int_as_float(rec.y) : 0.f;
        int pp = rec.x & 0x0FFFFFFF;
        x0[j]=pts[3*pp]; x1[j]=pts[3*pp+1]; x2[j]=pts[3*pp+2];
        int rd = ray_id[pp];
        x3[j]=vdirs[3*rd]; x4[j]=vdirs[3*rd+1]; x5[j]=vdirs[3*rd+2];
        ar[j]=0.f; ag[j]=0.f; ab[j]=0.f; aa[j]=0.f;
    }
    #pragma unroll 2
    for (int i=0;i<128;i++){
        float4 wa = WA[i], wb = WB[i], wc = WC[i];
        #pragma unroll
        for (int j=0;j<8;j++){
            float h = fmaf(x0[j],wa.x, fmaf(x1[j],wa.y, fmaf(x2[j],wa.z,
                      fmaf(x3[j],wa.w, fmaf(x4[j],wb.x, fmaf(x5[j],wb.y, wb.z))))));
            h = fmaxf(h, 0.f);
            ar[j] = fmaf(h, wc.x, ar[j]);
            ag[j] = fmaf(h, wc.y, ag[j]);
            ab[j] = fmaf(h, wc.z, ab[j]);
            aa[j] = fmaf(h, wb.w, aa[j]);
        }
    }
    #pragma unroll
    for (int j=0;j<8;j++){
        int idx = base + t + j*256;
        if (idx < n){
            float sr = __fdividef(1.0f, 1.0f + __expf(-ar[j]));
            float sg = __fdividef(1.0f, 1.0f + __expf(-ag[j]));
            float sb = __fdividef(1.0f, 1.0f + __expf(-ab[j]));
            float a  = raw2alpha_f(aa[j]);
            float g  = gg[j];
            int pp   = rid8[j] & 0x0FFFFFFF;
            int slot = ((unsigned)rid8[j]) >> 30;
            res[2*(size_t)pp + slot] = make_float4(g*sr, g*sg, g*sb, g*a);
        }
    }
}

// ---------------- kernel 6: final per-ray composite ----------------
__global__ __launch_bounds__(256) void k_scan1(const float4* __restrict__ res,
                                               const unsigned char* __restrict__ keep,
                                               const int* __restrict__ ray_off,
                                               const float* __restrict__ bg,
                                               float* __restrict__ out)
{
    int wid  = (blockIdx.x*blockDim.x + threadIdx.x) >> 6;   // wave = ray
    int lane = threadIdx.x & 63;
    if (wid >= NRAYS) return;
    int s = ray_off[wid], e = ray_off[wid+1];
    float carry = 1.f;
    float accx = 0.f, accy = 0.f, accz = 0.f;
    for (int c = s; c < e; c += 64){
        int p = c + lane;
        float4 v = make_float4(0.f,0.f,0.f,0.f);
        if (p < e && keep[p]){
            float4 v0 = res[2*(size_t)p];
            float4 v1 = res[2*(size_t)p + 1];
            v = make_float4(v0.x+v1.x, v0.y+v1.y, v0.z+v1.z, v0.w+v1.w);
        }
        float a = v.w;
        float f = 1.f - a;
        float incl = f;
        #pragma unroll
        for (int d=1; d<64; d<<=1){ float tt = __shfl_up(incl, d); if (lane >= d) incl *= tt; }
        float excl = __shfl_up(incl, 1); if (lane == 0) excl = 1.f;
        float w = a * carry * excl;
        accx = fmaf(w, v.x, accx);
        accy = fmaf(w, v.y, accy);
        accz = fmaf(w, v.z, accz);
        carry *= __shfl(incl, 63);
    }
    #pragma unroll
    for (int d=32; d; d>>=1){
        accx += __shfl_xor(accx, d);
        accy += __shfl_xor(accy, d);
        accz += __shfl_xor(accz, d);
    }
    if (lane == 0){
        out[3*wid+0] = accx + carry*bg[0];
        out[3*wid+1] = accy + carry*bg[1];
        out[3*wid+2] = accz + carry*bg[2];
    }
}

extern "C" void kernel_launch(void* const* d_in, const int* in_sizes, int n_in,
                              void* d_out, int out_size, void* d_ws, size_t ws_size,
                              hipStream_t stream)
{
    const float* pts    = (const float*)d_in[0];
    const float* vdirs  = (const float*)d_in[1];
    const float* bg     = (const float*)d_in[2];
    const float* Wd1    = (const float*)d_in[3];
    const float* bd1    = (const float*)d_in[4];
    const float* Wd2    = (const float*)d_in[5];
    const float* Wg     = (const float*)d_in[6];
    const float* We1    = (const float*)d_in[7];
    const float* be1    = (const float*)d_in[8];
    const float* Wrgb   = (const float*)d_in[9];
    const float* Walpha = (const float*)d_in[10];
    const int*   ray_id = (const int*)d_in[11];
    float* out = (float*)d_out;

    char* ws = (char*)d_ws;
    size_t off = 0;
    float* alpha0        = (float*)(ws + off); off += (size_t)PTOT*4;     // 4MB
    float* g0a           = (float*)(ws + off); off += (size_t)PTOT*4;     // 4MB
    int*   eea           = (int*)  (ws + off); off += (size_t)PTOT*4;     // 4MB
    unsigned char* keep  = (unsigned char*)(ws + off); off += (size_t)PTOT; // 1MB
    int*   ray_off       = (int*)  (ws + off); off += 65536;
    int*   cntA          = (int*)  (ws + off); off += 256;
    int*   offA          = (int*)  (ws + off); off += 256;
    int*   curA          = (int*)  (ws + off); off += 256;
    off = (off + 255) & ~(size_t)255;
    int2*  ent           = (int2*) (ws + off); off += (size_t)2*PTOT*8;   // 16MB
    float4* res          = (float4*)(ws + off); off += (size_t)2*PTOT*16; // 32MB

    hipMemsetAsync(cntA, 0, 8*sizeof(int), stream);

    k_point  <<<PTOT/2048, 256, 0, stream>>>(pts, vdirs, ray_id, Wd1, bd1, Wd2, Wg,
                                             alpha0, g0a, eea);
    k_rayoff <<<(NRAYS+256)/256, 256, 0, stream>>>(ray_id, ray_off);
    k_scan0  <<<NRAYS*64/256, 256, 0, stream>>>(alpha0, ray_off, keep);
    k_count  <<<PTOT/2048, 256, 0, stream>>>(keep, eea, cntA);
    k_offsets<<<1, 64, 0, stream>>>(cntA, offA, curA);
    k_fill   <<<PTOT/2048, 256, 0, stream>>>(keep, g0a, eea, offA, curA, ent);
    k_expert <<<8*512, 256, 0, stream>>>(ent, cntA, offA, pts, vdirs, ray_id,
                                         We1, be1, Wrgb, Walpha, res);
    k_scan1  <<<NRAYS*64/256, 256, 0, stream>>>(res, keep, ray_off, bg, out);
}